// Round 4
// baseline (225.532 us; speedup 1.0000x reference)
//
#include <hip/hip_runtime.h>

typedef float fvec4 __attribute__((ext_vector_type(4)));

#define NN 65536      // total nodes per side (B*NPG)
#define EE 1048576    // edges per side (B*NPG*DEG)
#define BB 128
#define NPG 512
#define EPG 8192      // edges per graph (NPG*DEG)

// ---- compute one 16-wide output chunk of xW into acc[4] (fvec4 each) ----
template <int FIN, int FOUT>
__device__ __forceinline__ void compute_acc(const float (&xin)[FIN], const float* __restrict__ w,
                                            int c, fvec4 (&acc)[4]) {
#pragma unroll
  for (int q = 0; q < 4; ++q) acc[q] = fvec4{0.f, 0.f, 0.f, 0.f};
  const float* wc = w + c * 16;
#pragma unroll
  for (int k = 0; k < FIN; ++k) {
    const fvec4* wr = reinterpret_cast<const fvec4*>(wc + (size_t)k * FOUT);
    const float xk = xin[k];
#pragma unroll
    for (int q = 0; q < 4; ++q) acc[q] += xk * wr[q];
  }
}

// ---- fused GCN layer, double-buffered msg, 1 barrier per chunk ----
// msg buffers: 512 rows x 16 floats, float4 XOR-swizzled on (row&3).
template <int FIN, int FOUT, bool RELU, bool LAST>
__device__ __forceinline__ void gcn_layer(const float (&xin)[FIN], float (&xout)[FOUT],
                                          const float* __restrict__ w, const float* __restrict__ bias,
                                          int start, int count, float inv_v, int slot,
                                          fvec4* __restrict__ msgA, fvec4* __restrict__ msgB,
                                          const int* __restrict__ sids,
                                          float* __restrict__ hs, int hb) {
  constexpr int NCH = FOUT / 16;
  const int v = threadIdx.x;
  fvec4 accCur[4], accNext[4];

  // prologue: chunk 0 messages
  compute_acc<FIN, FOUT>(xin, w, 0, accCur);
#pragma unroll
  for (int q = 0; q < 4; ++q) msgA[(v << 2) | (q ^ (v & 3))] = accCur[q] * inv_v;
  __syncthreads();

#pragma unroll
  for (int c = 0; c < NCH; ++c) {
    fvec4* const bufR = (c & 1) ? msgB : msgA;
    fvec4* const bufW = (c & 1) ? msgA : msgB;

    // next chunk's GEMM (pure VALU) — interleaves under this chunk's LDS gather
    if (c + 1 < NCH) compute_acc<FIN, FOUT>(xin, w, c + 1, accNext);

    if (!LAST || slot >= 0) {
      fvec4 s0 = {0.f, 0.f, 0.f, 0.f}, s1 = s0, s2 = s0, s3 = s0;
      int e = start;
      const int end = start + count;
#define ACC_EDGE(ID) { const int b_ = (ID) << 2; const int w_ = (ID) & 3;            \
      s0 += bufR[b_ | (0 ^ w_)]; s1 += bufR[b_ | (1 ^ w_)];                          \
      s2 += bufR[b_ | (2 ^ w_)]; s3 += bufR[b_ | (3 ^ w_)]; }
      for (; e + 4 <= end; e += 4) {
        const int i0 = sids[e], i1 = sids[e + 1], i2 = sids[e + 2], i3 = sids[e + 3];
        ACC_EDGE(i0) ACC_EDGE(i1) ACC_EDGE(i2) ACC_EDGE(i3)
      }
      for (; e < end; ++e) { const int i0 = sids[e]; ACC_EDGE(i0) }
#undef ACC_EDGE
      fvec4 s[4] = {s0, s1, s2, s3};
      const fvec4* bv = reinterpret_cast<const fvec4*>(bias + c * 16);
      const float i2 = inv_v * inv_v;
#pragma unroll
      for (int q = 0; q < 4; ++q) {
        fvec4 o = s[q] * inv_v + accCur[q] * i2 + bv[q];
        if (RELU) {
#pragma unroll
          for (int j = 0; j < 4; ++j) o[j] = fmaxf(o[j], 0.0f);
        }
#pragma unroll
        for (int j = 0; j < 4; ++j) xout[c * 16 + q * 4 + j] = o[j];
        if (slot >= 0) {
          fvec4* hp = reinterpret_cast<fvec4*>(hs + ((size_t)hb + slot) * FOUT + c * 16);
          hp[q] = o;
        }
      }
    }

    // publish next chunk's messages into the other buffer
    if (c + 1 < NCH) {
#pragma unroll
      for (int q = 0; q < 4; ++q) bufW[(v << 2) | (q ^ (v & 3))] = accNext[q] * inv_v;
    }
    __syncthreads();
    if (c + 1 < NCH) {
#pragma unroll
      for (int q = 0; q < 4; ++q) accCur[q] = accNext[q];
    }
  }
}

// ---------------- one block per (side, graph): CSR build in LDS + 3 GCN layers ----------------
__global__ __launch_bounds__(512) void k_all(const float* __restrict__ x_i, const float* __restrict__ x_j,
                                             const float* __restrict__ gw0, const float* __restrict__ gb0,
                                             const float* __restrict__ gw1, const float* __restrict__ gb1,
                                             const float* __restrict__ gw2, const float* __restrict__ gb2,
                                             const int* __restrict__ ei, const int* __restrict__ ej,
                                             float* __restrict__ hs0, float* __restrict__ hs1,
                                             float* __restrict__ hs2) {
  __shared__ int sids[EPG];        // 32 KB: per-dst bucketed local src ids
  __shared__ fvec4 msgA[NPG * 4];  // 32 KB: message buffer A
  __shared__ fvec4 msgB[NPG * 4];  // 32 KB: message buffer B (aliases dsts during prep)
  __shared__ int cnt[NPG];
  __shared__ int posb[NPG];
  __shared__ int wsum[8];
  int* const dsts = reinterpret_cast<int*>(msgB);  // prep-only staging

  const int side = blockIdx.x >> 7;
  const int g = blockIdx.x & 127;
  const float* __restrict__ x = side ? x_j : x_i;
  const int* __restrict__ eidx = side ? ej : ei;
  const int v = threadIdx.x;
  const int base = g * NPG;
  const int ebase = g * EPG;

  // ---- in-LDS degree count ----
  cnt[v] = 0;
  __syncthreads();
  for (int k = v; k < EPG; k += 512) {
    int d = eidx[EE + ebase + k] - base;
    dsts[k] = d;
    atomicAdd(&cnt[d], 1);
  }
  __syncthreads();

  // ---- in-block exclusive scan over 512 counts ----
  const int count = cnt[v];
  int xa = count;
  const int lane = v & 63;
#pragma unroll
  for (int d = 1; d < 64; d <<= 1) {
    int y = __shfl_up(xa, d, 64);
    if (lane >= d) xa += y;
  }
  const int wid = v >> 6;
  if (lane == 63) wsum[wid] = xa;
  __syncthreads();
  if (v == 0) {
    int a = 0;
#pragma unroll
    for (int i = 0; i < 8; ++i) { int tv = wsum[i]; wsum[i] = a; a += tv; }
  }
  __syncthreads();
  const int start = xa - count + wsum[wid];
  posb[v] = start;
  const float inv_v = rsqrtf((float)count + 1.0f);
  __syncthreads();

  // ---- CSR fill (bucket by dst) in LDS ----
  for (int k = v; k < EPG; k += 512) {
    int sv = eidx[ebase + k];
    int p = atomicAdd(&posb[dsts[k]], 1);
    sids[p] = sv - base;
  }

  // ---- issue this node's input row loads (fly during the barrier) ----
  float xin[64];
  {
    const fvec4* xv = reinterpret_cast<const fvec4*>(x + (size_t)(base + v) * 64);
#pragma unroll
    for (int k4 = 0; k4 < 16; ++k4) {
      fvec4 tv = xv[k4];
#pragma unroll
      for (int j = 0; j < 4; ++j) xin[4 * k4 + j] = tv[j];
    }
  }
  __syncthreads();

  // ---- sampled rows used by the bilinear-resized similarity image ----
  constexpr int srows[20] = {25, 26, 76, 77, 127, 128, 178, 179, 229, 230,
                             281, 282, 332, 333, 383, 384, 434, 435, 485, 486};
  int slot = -1;
#pragma unroll
  for (int i = 0; i < 20; ++i)
    if (v == srows[i]) slot = i;
  const int hb = (side * BB + g) * 20;

  // ---- three fused GCN layers, activations in registers ----
  float h0[64], h1[32], h2[16];
  gcn_layer<64, 64, true, false>(xin, h0, gw0, gb0, start, count, inv_v, slot, msgA, msgB, sids, hs0, hb);
  gcn_layer<64, 32, true, false>(h0, h1, gw1, gb1, start, count, inv_v, slot, msgA, msgB, sids, hs1, hb);
  gcn_layer<32, 16, false, true>(h1, h2, gw2, gb2, start, count, inv_v, slot, msgA, msgB, sids, hs2, hb);
}

// ---------------- head: sampled sim -> bilinear 10x10 -> conv3x3(1->8) -> MLP -> sigmoid ----------------
__global__ __launch_bounds__(256) void k_head(const float* __restrict__ hs0, const float* __restrict__ hs1,
                                              const float* __restrict__ hs2,
                                              const float* __restrict__ cw0, const float* __restrict__ cb0,
                                              const float* __restrict__ cw1, const float* __restrict__ cb1,
                                              const float* __restrict__ cw2, const float* __restrict__ cb2,
                                              const float* __restrict__ mw0, const float* __restrict__ mb0,
                                              const float* __restrict__ mw1, const float* __restrict__ mb1,
                                              const float* __restrict__ mw2, const float* __restrict__ mb2,
                                              const float* __restrict__ mw3, const float* __restrict__ mb3,
                                              const float* __restrict__ mw4, const float* __restrict__ mb4,
                                              const float* __restrict__ sw, const float* __restrict__ sb,
                                              float* __restrict__ out) {
  __shared__ float hi[2240];  // 20*64 + 20*32 + 20*16
  __shared__ float hj[2240];
  __shared__ float sim[400];
  __shared__ float simr[100];
  __shared__ float feat[2400];
  __shared__ float red[256];
  __shared__ float mbuf[60];
  const int b = blockIdx.x, t = threadIdx.x;

  for (int k = t; k < 1280; k += 256) {
    hi[k] = hs0[(size_t)(0 * BB + b) * 1280 + k];
    hj[k] = hs0[(size_t)(1 * BB + b) * 1280 + k];
  }
  for (int k = t; k < 640; k += 256) {
    hi[1280 + k] = hs1[(size_t)(0 * BB + b) * 640 + k];
    hj[1280 + k] = hs1[(size_t)(1 * BB + b) * 640 + k];
  }
  for (int k = t; k < 320; k += 256) {
    hi[1920 + k] = hs2[(size_t)(0 * BB + b) * 320 + k];
    hj[1920 + k] = hs2[(size_t)(1 * BB + b) * 320 + k];
  }
  __syncthreads();

  const int Fs[3] = {64, 32, 16};
  const int HOFF[3] = {0, 1280, 1920};
  const float* CW[3] = {cw0, cw1, cw2};
  const float* CB[3] = {cb0, cb1, cb2};

  for (int li = 0; li < 3; ++li) {
    const int F = Fs[li];
    const float* Hi = hi + HOFF[li];
    const float* Hj = hj + HOFF[li];
    for (int p = t; p < 400; p += 256) {
      int r = p / 20, cq = p % 20;
      float a = 0.0f;
      for (int d = 0; d < F; ++d) a += Hi[r * F + d] * Hj[cq * F + d];
      sim[p] = a;
    }
    __syncthreads();
    if (t < 100) {
      int oy = t / 10, ox = t % 10;
      float cy = (oy + 0.5f) * (512.0f / 10.0f) - 0.5f;
      float cx = (ox + 0.5f) * (512.0f / 10.0f) - 0.5f;
      float fy = cy - floorf(cy);
      float fx = cx - floorf(cx);
      int r0 = 2 * oy, c0 = 2 * ox;
      float s00 = sim[r0 * 20 + c0], s01 = sim[r0 * 20 + c0 + 1];
      float s10 = sim[(r0 + 1) * 20 + c0], s11 = sim[(r0 + 1) * 20 + c0 + 1];
      simr[t] = (1.0f - fy) * ((1.0f - fx) * s00 + fx * s01) + fy * ((1.0f - fx) * s10 + fx * s11);
    }
    __syncthreads();
    const float* cw = CW[li];
    const float* cb = CB[li];
    for (int idx = t; idx < 800; idx += 256) {
      int cch = idx / 100, rem = idx % 100, y = rem / 10, x = rem % 10;
      float a = cb[cch];
#pragma unroll
      for (int ky = 0; ky < 3; ++ky) {
#pragma unroll
        for (int kx = 0; kx < 3; ++kx) {
          int iy = y + ky - 1, ix = x + kx - 1;
          if (iy >= 0 && iy < 10 && ix >= 0 && ix < 10)
            a += cw[cch * 9 + ky * 3 + kx] * simr[iy * 10 + ix];
        }
      }
      feat[li * 800 + idx] = fmaxf(a, 0.0f);
    }
    __syncthreads();
  }

  // MLP0: 2400 -> 32, 8 partial sums per output
  {
    int f = t & 31, part = t >> 5;
    float a = 0.0f;
    int k0 = part * 300;
    for (int k = k0; k < k0 + 300; ++k) a += feat[k] * mw0[k * 32 + f];
    red[t] = a;
    __syncthreads();
    if (t < 32) {
      float s = mb0[t];
#pragma unroll
      for (int p = 0; p < 8; ++p) s += red[p * 32 + t];
      mbuf[t] = fmaxf(s, 0.0f);
    }
    __syncthreads();
  }
  if (t < 16) {
    float s = mb1[t];
    for (int k = 0; k < 32; ++k) s += mbuf[k] * mw1[k * 16 + t];
    mbuf[32 + t] = fmaxf(s, 0.0f);
  }
  __syncthreads();
  if (t < 8) {
    float s = mb2[t];
    for (int k = 0; k < 16; ++k) s += mbuf[32 + k] * mw2[k * 8 + t];
    mbuf[48 + t] = fmaxf(s, 0.0f);
  }
  __syncthreads();
  if (t < 4) {
    float s = mb3[t];
    for (int k = 0; k < 8; ++k) s += mbuf[48 + k] * mw3[k * 4 + t];
    mbuf[56 + t] = fmaxf(s, 0.0f);
  }
  __syncthreads();
  if (t == 0) {
    float s = mb4[0];
    for (int k = 0; k < 4; ++k) s += mbuf[56 + k] * mw4[k];
    s = fmaxf(s, 0.0f);
    float z = s * sw[0] + sb[0];
    out[b] = 1.0f / (1.0f + expf(-z));
  }
}

extern "C" void kernel_launch(void* const* d_in, const int* in_sizes, int n_in,
                              void* d_out, int out_size, void* d_ws, size_t ws_size,
                              hipStream_t stream) {
  (void)in_sizes; (void)n_in; (void)out_size; (void)ws_size;
  const float* x_i = (const float*)d_in[0];
  const float* x_j = (const float*)d_in[1];
  const float* gw0 = (const float*)d_in[2];
  const float* gb0 = (const float*)d_in[3];
  const float* gw1 = (const float*)d_in[4];
  const float* gb1 = (const float*)d_in[5];
  const float* gw2 = (const float*)d_in[6];
  const float* gb2 = (const float*)d_in[7];
  const float* cw0 = (const float*)d_in[8];
  const float* cb0 = (const float*)d_in[9];
  const float* cw1 = (const float*)d_in[10];
  const float* cb1 = (const float*)d_in[11];
  const float* cw2 = (const float*)d_in[12];
  const float* cb2 = (const float*)d_in[13];
  const float* mw0 = (const float*)d_in[14];
  const float* mb0 = (const float*)d_in[15];
  const float* mw1 = (const float*)d_in[16];
  const float* mb1 = (const float*)d_in[17];
  const float* mw2 = (const float*)d_in[18];
  const float* mb2 = (const float*)d_in[19];
  const float* mw3 = (const float*)d_in[20];
  const float* mb3 = (const float*)d_in[21];
  const float* mw4 = (const float*)d_in[22];
  const float* mb4 = (const float*)d_in[23];
  const float* scw = (const float*)d_in[24];
  const float* scb = (const float*)d_in[25];
  const int* ei = (const int*)d_in[26];
  const int* ej = (const int*)d_in[27];
  float* out = (float*)d_out;

  char* p = (char*)d_ws;
  auto take = [&](size_t bytes) {
    char* r = p;
    p += (bytes + 255) & ~(size_t)255;
    return r;
  };
  float* hs0 = (float*)take((size_t)2 * BB * 20 * 64 * 4);
  float* hs1 = (float*)take((size_t)2 * BB * 20 * 32 * 4);
  float* hs2 = (float*)take((size_t)2 * BB * 20 * 16 * 4);

  k_all<<<2 * BB, 512, 0, stream>>>(x_i, x_j, gw0, gb0, gw1, gb1, gw2, gb2,
                                    ei, ej, hs0, hs1, hs2);
  k_head<<<BB, 256, 0, stream>>>(hs0, hs1, hs2, cw0, cb0, cw1, cb1, cw2, cb2,
                                 mw0, mb0, mw1, mb1, mw2, mb2, mw3, mb3, mw4, mb4,
                                 scw, scb, out);
}

// Round 6
// 146.578 us; speedup vs baseline: 1.5387x; 1.5387x over previous
//
#include <hip/hip_runtime.h>

typedef float fvec4 __attribute__((ext_vector_type(4)));

#define NN 65536      // total nodes per side (B*NPG)
#define EE 1048576    // edges per side (B*NPG*DEG)
#define BB 128
#define NPG 512
#define EPG 8192      // edges per graph (NPG*DEG)

// ---- xW chunk (16 outputs) streaming the x-row from global (L2-resident after first pass) ----
template <int FOUT>
__device__ __forceinline__ void compute_acc_stream(const float* __restrict__ xg, const float* __restrict__ w,
                                                   int c, fvec4 (&acc)[4]) {
#pragma unroll
  for (int q = 0; q < 4; ++q) acc[q] = fvec4{0.f, 0.f, 0.f, 0.f};
  const float* wc = w + c * 16;
  const fvec4* xv = reinterpret_cast<const fvec4*>(xg);
#pragma unroll
  for (int k4 = 0; k4 < 16; ++k4) {
    fvec4 xq = xv[k4];
#pragma unroll
    for (int j = 0; j < 4; ++j) {
      const fvec4* wr = reinterpret_cast<const fvec4*>(wc + (size_t)(4 * k4 + j) * FOUT);
#pragma unroll
      for (int q = 0; q < 4; ++q) acc[q] += xq[j] * wr[q];
    }
  }
}

// ---- xW chunk from register-resident input row ----
template <int FIN, int FOUT>
__device__ __forceinline__ void compute_acc_regs(const float* xin, const float* __restrict__ w,
                                                 int c, fvec4 (&acc)[4]) {
#pragma unroll
  for (int q = 0; q < 4; ++q) acc[q] = fvec4{0.f, 0.f, 0.f, 0.f};
  const float* wc = w + c * 16;
#pragma unroll
  for (int k = 0; k < FIN; ++k) {
    const fvec4* wr = reinterpret_cast<const fvec4*>(wc + (size_t)k * FOUT);
    const float xk = xin[k];
#pragma unroll
    for (int q = 0; q < 4; ++q) acc[q] += xk * wr[q];
  }
}

// ---- publish chunk to TRANSPOSED msg buffer, gather, combine, write out ----
// msgT[f*NPG + row]: publish banks = v%32 (2-way, free); gather banks = row%32 (random ~2-way, free).
template <int FOUT, bool RELU, bool LAST>
__device__ __forceinline__ void agg_chunk(const fvec4 (&acc)[4], float* xout, int c,
                                          const float* __restrict__ bias,
                                          int start, int count, float inv_v, int slot,
                                          float* __restrict__ msgT, const int* __restrict__ sids,
                                          float* __restrict__ hs, int hb) {
  const int v = threadIdx.x;
#pragma unroll
  for (int q = 0; q < 4; ++q)
#pragma unroll
    for (int j = 0; j < 4; ++j)
      msgT[(q * 4 + j) * NPG + v] = acc[q][j] * inv_v;
  __syncthreads();
  if (!LAST || slot >= 0) {
    float s[16] = {0.f, 0.f, 0.f, 0.f, 0.f, 0.f, 0.f, 0.f,
                   0.f, 0.f, 0.f, 0.f, 0.f, 0.f, 0.f, 0.f};
    int e = start;
    const int end = start + count;
    for (; e + 2 <= end; e += 2) {
      const int a0 = sids[e], a1 = sids[e + 1];
#pragma unroll
      for (int f = 0; f < 16; ++f) s[f] += msgT[f * NPG + a0];
#pragma unroll
      for (int f = 0; f < 16; ++f) s[f] += msgT[f * NPG + a1];
    }
    if (e < end) {
      const int a0 = sids[e];
#pragma unroll
      for (int f = 0; f < 16; ++f) s[f] += msgT[f * NPG + a0];
    }
    const float i2 = inv_v * inv_v;
#pragma unroll
    for (int f = 0; f < 16; ++f) {
      float o = s[f] * inv_v + acc[f >> 2][f & 3] * i2 + bias[c * 16 + f];
      if (RELU) o = fmaxf(o, 0.f);
      xout[c * 16 + f] = o;
    }
    if (slot >= 0) {
      float* hp = hs + ((size_t)hb + slot) * FOUT + c * 16;
#pragma unroll
      for (int f = 0; f < 16; ++f) hp[f] = xout[c * 16 + f];
    }
  }
  __syncthreads();
}

// ---------------- one block per (side, graph): CSR build in LDS + 3 GCN layers ----------------
__global__ __launch_bounds__(512, 1) void k_all(const float* __restrict__ x_i, const float* __restrict__ x_j,
                                                const float* __restrict__ gw0, const float* __restrict__ gb0,
                                                const float* __restrict__ gw1, const float* __restrict__ gb1,
                                                const float* __restrict__ gw2, const float* __restrict__ gb2,
                                                const int* __restrict__ ei, const int* __restrict__ ej,
                                                float* __restrict__ hs0, float* __restrict__ hs1,
                                                float* __restrict__ hs2) {
  __shared__ int sids[EPG];           // 32 KB: per-dst bucketed local src ids
  __shared__ float msgT[16 * NPG];    // 32 KB: transposed message buffer (aliases dsts during prep)
  __shared__ int cnt[NPG];
  __shared__ int posb[NPG];
  __shared__ int wsum[8];
  int* const dsts = reinterpret_cast<int*>(msgT);  // prep-only staging

  const int side = blockIdx.x >> 7;
  const int g = blockIdx.x & 127;
  const float* __restrict__ x = side ? x_j : x_i;
  const int* __restrict__ eidx = side ? ej : ei;
  const int v = threadIdx.x;
  const int base = g * NPG;
  const int ebase = g * EPG;

  // ---- in-LDS degree count ----
  cnt[v] = 0;
  __syncthreads();
  for (int k = v; k < EPG; k += 512) {
    int d = eidx[EE + ebase + k] - base;
    dsts[k] = d;
    atomicAdd(&cnt[d], 1);
  }
  __syncthreads();

  // ---- in-block exclusive scan over 512 counts ----
  const int count = cnt[v];
  int xa = count;
  const int lane = v & 63;
#pragma unroll
  for (int d = 1; d < 64; d <<= 1) {
    int y = __shfl_up(xa, d, 64);
    if (lane >= d) xa += y;
  }
  const int wid = v >> 6;
  if (lane == 63) wsum[wid] = xa;
  __syncthreads();
  if (v == 0) {
    int a = 0;
#pragma unroll
    for (int i = 0; i < 8; ++i) { int tv = wsum[i]; wsum[i] = a; a += tv; }
  }
  __syncthreads();
  const int start = xa - count + wsum[wid];
  posb[v] = start;
  const float inv_v = rsqrtf((float)count + 1.0f);
  __syncthreads();

  // ---- CSR fill (bucket by dst) in LDS ----
  for (int k = v; k < EPG; k += 512) {
    int sv = eidx[ebase + k];
    int p = atomicAdd(&posb[dsts[k]], 1);
    sids[p] = sv - base;
  }
  __syncthreads();

  // ---- sampled rows used by the bilinear-resized similarity image ----
  constexpr int srows[20] = {25, 26, 76, 77, 127, 128, 178, 179, 229, 230,
                             281, 282, 332, 333, 383, 384, 434, 435, 485, 486};
  int slot = -1;
#pragma unroll
  for (int i = 0; i < 20; ++i)
    if (v == srows[i]) slot = i;
  const int hb = (side * BB + g) * 20;

  // ---- three fused GCN layers ----
  float h0[64], h1[32], h2[16];
  const float* xg = x + (size_t)(base + v) * 64;
#pragma unroll
  for (int c = 0; c < 4; ++c) {
    fvec4 acc[4];
    compute_acc_stream<64>(xg, gw0, c, acc);
    agg_chunk<64, true, false>(acc, h0, c, gb0, start, count, inv_v, slot, msgT, sids, hs0, hb);
  }
#pragma unroll
  for (int c = 0; c < 2; ++c) {
    fvec4 acc[4];
    compute_acc_regs<64, 32>(h0, gw1, c, acc);
    agg_chunk<32, true, false>(acc, h1, c, gb1, start, count, inv_v, slot, msgT, sids, hs1, hb);
  }
  {
    fvec4 acc[4];
    compute_acc_regs<32, 16>(h1, gw2, 0, acc);
    agg_chunk<16, false, true>(acc, h2, 0, gb2, start, count, inv_v, slot, msgT, sids, hs2, hb);
  }
}

// ---------------- head: sampled sim -> bilinear 10x10 -> conv3x3(1->8) -> MLP -> sigmoid ----------------
__global__ __launch_bounds__(256) void k_head(const float* __restrict__ hs0, const float* __restrict__ hs1,
                                              const float* __restrict__ hs2,
                                              const float* __restrict__ cw0, const float* __restrict__ cb0,
                                              const float* __restrict__ cw1, const float* __restrict__ cb1,
                                              const float* __restrict__ cw2, const float* __restrict__ cb2,
                                              const float* __restrict__ mw0, const float* __restrict__ mb0,
                                              const float* __restrict__ mw1, const float* __restrict__ mb1,
                                              const float* __restrict__ mw2, const float* __restrict__ mb2,
                                              const float* __restrict__ mw3, const float* __restrict__ mb3,
                                              const float* __restrict__ mw4, const float* __restrict__ mb4,
                                              const float* __restrict__ sw, const float* __restrict__ sb,
                                              float* __restrict__ out) {
  __shared__ float hi[2240];  // 20*64 + 20*32 + 20*16
  __shared__ float hj[2240];
  __shared__ float sim[400];
  __shared__ float simr[100];
  __shared__ float feat[2400];
  __shared__ float red[256];
  __shared__ float mbuf[60];
  const int b = blockIdx.x, t = threadIdx.x;

  for (int k = t; k < 1280; k += 256) {
    hi[k] = hs0[(size_t)(0 * BB + b) * 1280 + k];
    hj[k] = hs0[(size_t)(1 * BB + b) * 1280 + k];
  }
  for (int k = t; k < 640; k += 256) {
    hi[1280 + k] = hs1[(size_t)(0 * BB + b) * 640 + k];
    hj[1280 + k] = hs1[(size_t)(1 * BB + b) * 640 + k];
  }
  for (int k = t; k < 320; k += 256) {
    hi[1920 + k] = hs2[(size_t)(0 * BB + b) * 320 + k];
    hj[1920 + k] = hs2[(size_t)(1 * BB + b) * 320 + k];
  }
  __syncthreads();

  const int Fs[3] = {64, 32, 16};
  const int HOFF[3] = {0, 1280, 1920};
  const float* CW[3] = {cw0, cw1, cw2};
  const float* CB[3] = {cb0, cb1, cb2};

  for (int li = 0; li < 3; ++li) {
    const int F = Fs[li];
    const float* Hi = hi + HOFF[li];
    const float* Hj = hj + HOFF[li];
    for (int p = t; p < 400; p += 256) {
      int r = p / 20, cq = p % 20;
      float a = 0.0f;
      for (int d = 0; d < F; ++d) a += Hi[r * F + d] * Hj[cq * F + d];
      sim[p] = a;
    }
    __syncthreads();
    if (t < 100) {
      int oy = t / 10, ox = t % 10;
      float cy = (oy + 0.5f) * (512.0f / 10.0f) - 0.5f;
      float cx = (ox + 0.5f) * (512.0f / 10.0f) - 0.5f;
      float fy = cy - floorf(cy);
      float fx = cx - floorf(cx);
      int r0 = 2 * oy, c0 = 2 * ox;
      float s00 = sim[r0 * 20 + c0], s01 = sim[r0 * 20 + c0 + 1];
      float s10 = sim[(r0 + 1) * 20 + c0], s11 = sim[(r0 + 1) * 20 + c0 + 1];
      simr[t] = (1.0f - fy) * ((1.0f - fx) * s00 + fx * s01) + fy * ((1.0f - fx) * s10 + fx * s11);
    }
    __syncthreads();
    const float* cw = CW[li];
    const float* cb = CB[li];
    for (int idx = t; idx < 800; idx += 256) {
      int cch = idx / 100, rem = idx % 100, y = rem / 10, x = rem % 10;
      float a = cb[cch];
#pragma unroll
      for (int ky = 0; ky < 3; ++ky) {
#pragma unroll
        for (int kx = 0; kx < 3; ++kx) {
          int iy = y + ky - 1, ix = x + kx - 1;
          if (iy >= 0 && iy < 10 && ix >= 0 && ix < 10)
            a += cw[cch * 9 + ky * 3 + kx] * simr[iy * 10 + ix];
        }
      }
      feat[li * 800 + idx] = fmaxf(a, 0.0f);
    }
    __syncthreads();
  }

  // MLP0: 2400 -> 32, 8 partial sums per output
  {
    int f = t & 31, part = t >> 5;
    float a = 0.0f;
    int k0 = part * 300;
    for (int k = k0; k < k0 + 300; ++k) a += feat[k] * mw0[k * 32 + f];
    red[t] = a;
    __syncthreads();
    if (t < 32) {
      float s = mb0[t];
#pragma unroll
      for (int p = 0; p < 8; ++p) s += red[p * 32 + t];
      mbuf[t] = fmaxf(s, 0.0f);
    }
    __syncthreads();
  }
  if (t < 16) {
    float s = mb1[t];
    for (int k = 0; k < 32; ++k) s += mbuf[k] * mw1[k * 16 + t];
    mbuf[32 + t] = fmaxf(s, 0.0f);
  }
  __syncthreads();
  if (t < 8) {
    float s = mb2[t];
    for (int k = 0; k < 16; ++k) s += mbuf[32 + k] * mw2[k * 8 + t];
    mbuf[48 + t] = fmaxf(s, 0.0f);
  }
  __syncthreads();
  if (t < 4) {
    float s = mb3[t];
    for (int k = 0; k < 8; ++k) s += mbuf[48 + k] * mw3[k * 4 + t];
    mbuf[56 + t] = fmaxf(s, 0.0f);
  }
  __syncthreads();
  if (t == 0) {
    float s = mb4[0];
    for (int k = 0; k < 4; ++k) s += mbuf[56 + k] * mw4[k];
    s = fmaxf(s, 0.0f);
    float z = s * sw[0] + sb[0];
    out[b] = 1.0f / (1.0f + expf(-z));
  }
}

extern "C" void kernel_launch(void* const* d_in, const int* in_sizes, int n_in,
                              void* d_out, int out_size, void* d_ws, size_t ws_size,
                              hipStream_t stream) {
  (void)in_sizes; (void)n_in; (void)out_size; (void)ws_size;
  const float* x_i = (const float*)d_in[0];
  const float* x_j = (const float*)d_in[1];
  const float* gw0 = (const float*)d_in[2];
  const float* gb0 = (const float*)d_in[3];
  const float* gw1 = (const float*)d_in[4];
  const float* gb1 = (const float*)d_in[5];
  const float* gw2 = (const float*)d_in[6];
  const float* gb2 = (const float*)d_in[7];
  const float* cw0 = (const float*)d_in[8];
  const float* cb0 = (const float*)d_in[9];
  const float* cw1 = (const float*)d_in[10];
  const float* cb1 = (const float*)d_in[11];
  const float* cw2 = (const float*)d_in[12];
  const float* cb2 = (const float*)d_in[13];
  const float* mw0 = (const float*)d_in[14];
  const float* mb0 = (const float*)d_in[15];
  const float* mw1 = (const float*)d_in[16];
  const float* mb1 = (const float*)d_in[17];
  const float* mw2 = (const float*)d_in[18];
  const float* mb2 = (const float*)d_in[19];
  const float* mw3 = (const float*)d_in[20];
  const float* mb3 = (const float*)d_in[21];
  const float* mw4 = (const float*)d_in[22];
  const float* mb4 = (const float*)d_in[23];
  const float* scw = (const float*)d_in[24];
  const float* scb = (const float*)d_in[25];
  const int* ei = (const int*)d_in[26];
  const int* ej = (const int*)d_in[27];
  float* out = (float*)d_out;

  char* p = (char*)d_ws;
  auto take = [&](size_t bytes) {
    char* r = p;
    p += (bytes + 255) & ~(size_t)255;
    return r;
  };
  float* hs0 = (float*)take((size_t)2 * BB * 20 * 64 * 4);
  float* hs1 = (float*)take((size_t)2 * BB * 20 * 32 * 4);
  float* hs2 = (float*)take((size_t)2 * BB * 20 * 16 * 4);

  k_all<<<2 * BB, 512, 0, stream>>>(x_i, x_j, gw0, gb0, gw1, gb1, gw2, gb2,
                                    ei, ej, hs0, hs1, hs2);
  k_head<<<BB, 256, 0, stream>>>(hs0, hs1, hs2, cw0, cb0, cw1, cb1, cw2, cb2,
                                 mw0, mb0, mw1, mb1, mw2, mb2, mw3, mb3, mw4, mb4,
                                 scw, scb, out);
}